// Round 7
// baseline (160.814 us; speedup 1.0000x reference)
//
#include <hip/hip_runtime.h>

typedef _Float16 f16;
typedef _Float16 half8 __attribute__((ext_vector_type(8)));
typedef float f32x4 __attribute__((ext_vector_type(4)));
typedef float f32x16 __attribute__((ext_vector_type(16)));
typedef unsigned u32x4 __attribute__((ext_vector_type(4)));

#define LDW 72  // K-tile / Om / wT4 leading dim (f16)
#define LDV 36  // V-tile leading dim (32 kv cols + 4 pad)

// ---------------- K1: BatchNorm statistics -> per-block partials (r4 verbatim) ----------------
__global__ __launch_bounds__(256) void k_bnstats(const float* __restrict__ x, float* __restrict__ part){
    __shared__ float red[512];
    int t = threadIdx.x;
    int c = t & 63, rg = t >> 6;
    int rb = blockIdx.x * 64;
    float s = 0.f, s2 = 0.f;
    for(int r = rg; r < 64; r += 4){
        float v = x[(rb + r) * 64 + c];
        s += v; s2 += v * v;
    }
    red[t] = s; red[256 + t] = s2;
    __syncthreads();
    if(t < 128){
        int c2 = t & 63, h = t >> 6;
        float a = red[h * 256 + c2] + red[h * 256 + c2 + 64] + red[h * 256 + c2 + 128] + red[h * 256 + c2 + 192];
        part[blockIdx.x * 128 + t] = a;
    }
}

// ---------------- K2: partial-reduce + BN apply + QKV projections (r4 verbatim) ----------------
__global__ __launch_bounds__(256) void k_qkv(
    const float* __restrict__ x,
    const float* __restrict__ w1, const float* __restrict__ w2, const float* __restrict__ w3,
    const float* __restrict__ b1, const float* __restrict__ b2, const float* __restrict__ b3,
    const float* __restrict__ gamma, const float* __restrict__ beta,
    const float* __restrict__ part,
    f16* __restrict__ Q, f16* __restrict__ Kx, f16* __restrict__ Vt){
    __shared__ f16 wT[3 * 64 * LDW];
    __shared__ float sc[64], sh[64], bb[3][64];
    __shared__ float psum[128];
    int t = threadIdx.x;
    for(int i = t; i < 3 * 4096; i += 256){
        int j = i >> 12, e = i & 4095, k = e >> 6, n = e & 63;
        const float* wp = (j == 0) ? w1 : ((j == 1) ? w2 : w3);
        wT[j * 64 * LDW + n * LDW + k] = (f16)wp[e];
    }
    if(t < 128){
        float a0 = 0.f, a1 = 0.f, a2 = 0.f, a3 = 0.f;
        for(int b = 0; b < 256; b += 4){
            a0 += part[b * 128 + t];       a1 += part[(b + 1) * 128 + t];
            a2 += part[(b + 2) * 128 + t]; a3 += part[(b + 3) * 128 + t];
        }
        psum[t] = (a0 + a1) + (a2 + a3);
    }
    __syncthreads();
    if(t < 64){
        float mean = psum[t] * (1.f / 16384.f);
        float var  = psum[64 + t] * (1.f / 16384.f) - mean * mean;
        float s = gamma[t] * rsqrtf(var + 1e-5f);
        sc[t] = s;
        sh[t] = beta[t] - mean * s;
        bb[0][t] = b1[t]; bb[1][t] = b2[t]; bb[2][t] = b3[t];
    }
    __syncthreads();
    int w = t >> 6, lane = t & 63, quad = lane >> 4, l15 = lane & 15;
    int rowb = blockIdx.x * 64 + w * 16;
    int arow = rowb + l15;
    half8 a[2];
    #pragma unroll
    for(int kc = 0; kc < 2; kc++){
        f32x4 x0 = *(const f32x4*)&x[arow * 64 + kc * 32 + quad * 8];
        f32x4 x1 = *(const f32x4*)&x[arow * 64 + kc * 32 + quad * 8 + 4];
        half8 h;
        #pragma unroll
        for(int j = 0; j < 8; j++){
            int c = kc * 32 + quad * 8 + j;
            float xv = (j < 4) ? x0[j & 3] : x1[j & 3];
            h[j] = (f16)(xv * sc[c] + sh[c]);
        }
        a[kc] = h;
    }
    const f32x4 vzero = {0.f, 0.f, 0.f, 0.f};
    f32x4 acc[3][4];
    #pragma unroll
    for(int m = 0; m < 3; m++){
        #pragma unroll
        for(int nt = 0; nt < 4; nt++){
            acc[m][nt] = vzero;
            #pragma unroll
            for(int kc = 0; kc < 2; kc++){
                half8 bfr = *(half8*)&wT[m * 64 * LDW + (nt * 16 + l15) * LDW + kc * 32 + quad * 8];
                acc[m][nt] = __builtin_amdgcn_mfma_f32_16x16x32_f16(a[kc], bfr, acc[m][nt], 0, 0, 0);
            }
        }
    }
    const float qs = 0.18033688011112043f;  // log2(e)/8
    #pragma unroll
    for(int nt = 0; nt < 4; nt++){
        #pragma unroll
        for(int r = 0; r < 4; r++){
            int row = rowb + quad * 4 + r;
            int col = nt * 16 + l15;
            Q[row * 64 + col]  = (f16)((acc[0][nt][r] + bb[0][col]) * qs);
            Kx[row * 64 + col] = (f16)(acc[1][nt][r] + bb[1][col]);
            Vt[((row >> 12) * 64 + col) * 4096 + (row & 4095)] = (f16)(acc[2][nt][r] + bb[2][col]);
        }
    }
}

// ---------------- K3: attention with in-block split-K=4 (one KV quarter per wave) + fused merge/W4/residual ----
// grid 512: 32 Q-rows per block (shared by all 4 waves), wave w sweeps kv rows [w*1024, w*1024+1024).
// Wave-private double-buffered LDS streams -> ZERO barriers in the sweep.
// No-max softmax => partials across waves merge by simple addition (same exp scale).
// Tail: waves 1-3 dump (o,l) to LDS; wave 0 totals+normalizes into Om; waves 0-1 project W4 + bias + residual.
__global__ __launch_bounds__(256, 2) void k_attn(
    const f16* __restrict__ Q, const f16* __restrict__ Kx, const f16* __restrict__ Vt,
    const float* __restrict__ w4, const float* __restrict__ b4,
    const float* __restrict__ x, float* __restrict__ out){
    __shared__ char smem[73728] __attribute__((aligned(16)));
    f16* KVf = (f16*)smem;
    int t = threadIdx.x, bid = blockIdx.x;
    int w = t >> 6, lane = t & 63, l31 = lane & 31, hi = lane >> 5, quad = lane >> 4, l15 = lane & 15;
    int b = bid >> 7;                 // image (128 blocks per image)
    int qrow0 = bid * 32;             // global Q-row base of this block
    int kvbase = w * 1024;            // this wave's KV quarter
    const int WSTR = 9216;            // f16 per wave region (2 bufs x (32*LDW + 64*LDV))
    const int BSTR = 4608;            // f16 per buffer
    int wbase = w * WSTR;

    // wT4 reg-stage: issue global loads now, write to LDS after the sweep (T14)
    f16 wreg[16];
    #pragma unroll
    for(int i = 0; i < 16; i++) wreg[i] = (f16)w4[t + i * 256];

    // Q fragments (B-operand): lane holds qrow = qrow0+l31, d-elems dc*16 + hi*8 .. +7
    half8 aq[4];
    #pragma unroll
    for(int dc = 0; dc < 4; dc++)
        aq[dc] = *(const half8*)&Q[(qrow0 + l31) * 64 + dc * 16 + hi * 8];

    // wave-private staging: per tile 512 x 16B chunks (256 K + 256 V^T), 8 chunks/lane
    const f16* gsrc[8];
    int loff[8], gstep[8];
    #pragma unroll
    for(int i = 0; i < 8; i++){
        int idx = lane + i * 64;             // 0..511
        if(idx < 256){                       // K: 32 rows x 8 chunks of 8 f16
            int rr = idx >> 3, c8 = idx & 7;
            loff[i]  = wbase + rr * LDW + c8 * 8;
            gsrc[i]  = &Kx[(b * 4096 + kvbase + rr) * 64 + c8 * 8];
            gstep[i] = 32 * 64;
        } else {                             // V^T: 64 d-rows x 4 chunks of 8 f16
            int v = idx - 256;
            int rr = v >> 2, c4 = v & 3;
            loff[i]  = wbase + 32 * LDW + rr * LDV + c4 * 8;
            gsrc[i]  = &Vt[(b * 64 + rr) * 4096 + kvbase + c4 * 8];
            gstep[i] = 32;
        }
    }
    half8 pre[8];
    #pragma unroll
    for(int i = 0; i < 8; i++){ pre[i] = *(const half8*)gsrc[i]; gsrc[i] += gstep[i]; }
    #pragma unroll
    for(int i = 0; i < 8; i++) *(half8*)&KVf[loff[i]] = pre[i];   // buffer 0

    f32x16 o[2];
    #pragma unroll
    for(int dt = 0; dt < 2; dt++)
        #pragma unroll
        for(int r = 0; r < 16; r++) o[dt][r] = 0.f;
    float lp = 0.f;

    int cur = 0;
    for(int j = 0; j < 32; j++){              // 32 tiles of 32 kv rows = 1024
        if(j < 31){
            #pragma unroll
            for(int i = 0; i < 8; i++){ pre[i] = *(const half8*)gsrc[i]; gsrc[i] += gstep[i]; }
        }
        const f16* Kb = KVf + wbase + cur * BSTR;
        const f16* Vb = Kb + 32 * LDW;
        // K fragments (A-operand): lane holds kcol = l31 (local), d-elems dc*16 + hi*8
        half8 ak[4];
        #pragma unroll
        for(int dc = 0; dc < 4; dc++)
            ak[dc] = *(const half8*)&Kb[l31 * LDW + dc * 16 + hi * 8];
        // V fragments (B-operand): lane holds d = dt*32+l31, kv-local kc*16 + hi*8
        half8 vb[2][2];
        #pragma unroll
        for(int kc = 0; kc < 2; kc++)
            #pragma unroll
            for(int dt = 0; dt < 2; dt++)
                vb[kc][dt] = *(const half8*)&Vb[(dt * 32 + l31) * LDV + kc * 16 + hi * 8];
        f32x16 s;
        #pragma unroll
        for(int r = 0; r < 16; r++) s[r] = 0.f;
        #pragma unroll
        for(int dc = 0; dc < 4; dc++)
            s = __builtin_amdgcn_mfma_f32_32x32x16_f16(ak[dc], aq[dc], s, 0, 0, 0);
        // S^T layout: lane's 16 values belong to qrow = qrow0+l31; kcol_local = (r&3)+8*(r>>2)+4*hi
        float pf[16], ls = 0.f;
        #pragma unroll
        for(int r = 0; r < 16; r++){
            float p = __builtin_amdgcn_exp2f(fminf(s[r], 15.f));
            pf[r] = p; ls += p;
        }
        lp += ls;
        unsigned wv[4][2];
        #pragma unroll
        for(int g = 0; g < 4; g++){
            wv[g][0] = __builtin_bit_cast(unsigned, __builtin_amdgcn_cvt_pkrtz(pf[4*g+0], pf[4*g+1]));
            wv[g][1] = __builtin_bit_cast(unsigned, __builtin_amdgcn_cvt_pkrtz(pf[4*g+2], pf[4*g+3]));
        }
        #pragma unroll
        for(int kc = 0; kc < 2; kc++){
            unsigned x0 = wv[2*kc][0], y0 = wv[2*kc+1][0];
            unsigned x1 = wv[2*kc][1], y1 = wv[2*kc+1][1];
            asm("v_permlane32_swap_b32 %0, %1" : "+v"(x0), "+v"(y0));
            asm("v_permlane32_swap_b32 %0, %1" : "+v"(x1), "+v"(y1));
            u32x4 pw = {x0, x1, y0, y1};
            half8 pa = __builtin_bit_cast(half8, pw);
            #pragma unroll
            for(int dt = 0; dt < 2; dt++)
                o[dt] = __builtin_amdgcn_mfma_f32_32x32x16_f16(pa, vb[kc][dt], o[dt], 0, 0, 0);
        }
        if(j < 31){
            f16* wb = KVf + (cur ^ 1) * BSTR;   // + loff already has wbase
            #pragma unroll
            for(int i = 0; i < 8; i++) *(half8*)(wb + loff[i]) = pre[i];
        }
        cur ^= 1;
    }

    // ---------------- in-block merge ----------------
    float v = lp + __shfl_xor(lp, 32);          // per-row partial sum, symmetric across lane halves
    if(w > 0){                                  // waves 1-3: dump raw partials into own (now dead) KV region
        float* op  = (float*)(smem + w * 18432);
        float* lpp = (float*)(smem + w * 18432 + 8192);
        #pragma unroll
        for(int r = 0; r < 16; r++){
            int qrl = (r & 3) + 8 * (r >> 2) + 4 * hi;
            #pragma unroll
            for(int dt = 0; dt < 2; dt++)
                op[qrl * 64 + dt * 32 + l31] = o[dt][r];
        }
        if(hi == 0) lpp[l31] = v;
    }
    __syncthreads();
    // all threads: write staged w4 into LDS (wave-0 region is dead now)
    f16* wT4 = (f16*)smem;                      // [0, 9216)
    #pragma unroll
    for(int i = 0; i < 16; i++){
        int idx = t + i * 256, k = idx >> 6, n = idx & 63;
        wT4[n * LDW + k] = wreg[i];
    }
    f16* Om = (f16*)(smem + 9216);              // [9216, 13824): 32 x LDW f16
    if(w == 0){                                 // wave 0: total + normalize
        float vtot = v;
        #pragma unroll
        for(int m = 1; m < 4; m++) vtot += ((const float*)(smem + m * 18432 + 8192))[l31];
        #pragma unroll
        for(int r = 0; r < 16; r++){
            int qrl = (r & 3) + 8 * (r >> 2) + 4 * hi;
            float inv = __builtin_amdgcn_rcpf(__shfl(vtot, qrl));
            #pragma unroll
            for(int dt = 0; dt < 2; dt++){
                float tot = o[dt][r];
                #pragma unroll
                for(int m = 1; m < 4; m++)
                    tot += ((const float*)(smem + m * 18432))[qrl * 64 + dt * 32 + l31];
                Om[qrl * LDW + dt * 32 + l31] = (f16)(tot * inv);
            }
        }
    }
    __syncthreads();
    // waves 0-1: W4 projection (16 rows each) + bias + residual
    if(w < 2){
        half8 a[2];
        #pragma unroll
        for(int kc = 0; kc < 2; kc++)
            a[kc] = *(half8*)&Om[(w * 16 + l15) * LDW + kc * 32 + quad * 8];
        #pragma unroll
        for(int nt = 0; nt < 4; nt++){
            f32x4 y = {0.f, 0.f, 0.f, 0.f};
            #pragma unroll
            for(int kc = 0; kc < 2; kc++){
                half8 bfr = *(half8*)&wT4[(nt * 16 + l15) * LDW + kc * 32 + quad * 8];
                y = __builtin_amdgcn_mfma_f32_16x16x32_f16(a[kc], bfr, y, 0, 0, 0);
            }
            #pragma unroll
            for(int r = 0; r < 4; r++){
                int row = qrow0 + w * 16 + quad * 4 + r;
                int col = nt * 16 + l15;
                out[row * 64 + col] = y[r] + b4[col] + x[row * 64 + col];
            }
        }
    }
}

extern "C" void kernel_launch(void* const* d_in, const int* in_sizes, int n_in,
                              void* d_out, int out_size, void* d_ws, size_t ws_size,
                              hipStream_t stream){
    (void)in_sizes; (void)n_in; (void)out_size; (void)ws_size;
    const float* x  = (const float*)d_in[0];
    const float* w1 = (const float*)d_in[1];
    const float* w2 = (const float*)d_in[2];
    const float* w3 = (const float*)d_in[3];
    const float* w4 = (const float*)d_in[4];
    const float* b1 = (const float*)d_in[5];
    const float* b2 = (const float*)d_in[6];
    const float* b3 = (const float*)d_in[7];
    const float* b4 = (const float*)d_in[8];
    const float* gm = (const float*)d_in[9];
    const float* bt = (const float*)d_in[10];
    char* ws = (char*)d_ws;
    f16* Q    = (f16*)(ws);
    f16* Kx   = (f16*)(ws + (size_t)(2u << 20));
    f16* Vt   = (f16*)(ws + (size_t)(4u << 20));
    float* part = (float*)(ws + (size_t)(6u << 20));   // 256 x 128 f32

    hipLaunchKernelGGL(k_bnstats, dim3(256), dim3(256), 0, stream, x, part);
    hipLaunchKernelGGL(k_qkv,     dim3(256), dim3(256), 0, stream, x, w1, w2, w3, b1, b2, b3, gm, bt, part, Q, Kx, Vt);
    hipLaunchKernelGGL(k_attn,    dim3(512), dim3(256), 0, stream, Q, Kx, Vt, w4, b4, x, (float*)d_out);
}